// Round 1
// baseline (501.244 us; speedup 1.0000x reference)
//
#include <hip/hip_runtime.h>

// ---------------- types ----------------
using u16    = unsigned short;
using u32    = unsigned int;
using bf16x8 = __attribute__((ext_vector_type(8))) __bf16;
using f32x4  = __attribute__((ext_vector_type(4))) float;
using u16x4  = __attribute__((ext_vector_type(4))) u16;
using u16x8  = __attribute__((ext_vector_type(8))) u16;

__device__ __forceinline__ u16 f32_to_bf16(float f) {
    u32 u = __float_as_uint(f);
    u32 r = (u + 0x7FFFu + ((u >> 16) & 1u)) >> 16;  // RNE
    return (u16)r;
}

// async global->LDS, 16B per lane (literal size required)
__device__ __forceinline__ void gld_lds16(const void* g, void* l) {
    __builtin_amdgcn_global_load_lds(
        (const __attribute__((address_space(1))) u32*)g,
        (__attribute__((address_space(3))) u32*)l,
        16, 0, 0);
}

// Cl(3,0) reorder sign for e_a * e_b; metric (1,1,1) contributes nothing.
// a,b < 8 so only shifts 1,2 matter.
__device__ __forceinline__ float cl3_sign(int a, int b) {
    int swaps = __popc((a >> 1) & b) + __popc((a >> 2) & b);
    return (swaps & 1) ? -1.0f : 1.0f;
}

// ---------------- prep: out[0] = x (fp32 copy), A0 = bf16(x) ----------------
// x: [2048, 512, 8] fp32 = 8,388,608 elems; 4 per thread -> 2,097,152 threads
__global__ __launch_bounds__(256) void prep_kernel(
    const float* __restrict__ x, float* __restrict__ out0, u16* __restrict__ A0)
{
    const int t = blockIdx.x * 256 + threadIdx.x;
    const float4 v = reinterpret_cast<const float4*>(x)[t];
    reinterpret_cast<float4*>(out0)[t] = v;
    u16x4 b;
    b.x = f32_to_bf16(v.x);
    b.y = f32_to_bf16(v.y);
    b.z = f32_to_bf16(v.z);
    b.w = f32_to_bf16(v.w);
    reinterpret_cast<u16x4*>(A0)[t] = b;
}

// ---------------- expand: Wmat[(o*8+k), (i*8+p)] = sign(p,p^k) * w[o,i,p^k] ----------------
// w: [512, 512, 8] fp32; Wmat: [4096, 4096] bf16 (B-transposed layout, K-contiguous)
// thread t: n = t>>9 (row of Wmat), i = t&511; reads 8 floats, writes 8 bf16 (16B)
__global__ __launch_bounds__(256) void expand_kernel(
    const float* __restrict__ w, u16* __restrict__ Wm)
{
    const int t  = blockIdx.x * 256 + threadIdx.x;   // 0 .. 2,097,151
    const int n  = t >> 9;
    const int i  = t & 511;
    const int o  = n >> 3;
    const int kb = n & 7;
    const float* src = w + ((size_t)(o * 512 + i) << 3);
    const float4 w0 = reinterpret_cast<const float4*>(src)[0];
    const float4 w1 = reinterpret_cast<const float4*>(src)[1];
    float wv[8] = {w0.x, w0.y, w0.z, w0.w, w1.x, w1.y, w1.z, w1.w};
    u16x8 ov;
    #pragma unroll
    for (int p = 0; p < 8; ++p) {
        const int q = p ^ kb;
        ov[p] = f32_to_bf16(cl3_sign(p, q) * wv[q]);
    }
    reinterpret_cast<u16x8*>(Wm)[t] = ov;  // offset n*4096 + i*8 = t*8
}

// ---------------- GEMM: C[2048,4096] = A[2048,4096] x Wmat^T ----------------
// m97-class structure: 128x128 tile, BK=32, 4 waves (64x64 each, 4x4 frags of
// 16x16x32 bf16 MFMA), global_load_lds width-16 staging, 2-barrier K-loop.
// Epilogue: fp32 -> C (d_out slice), bf16 -> An (next layer activation, may be null).
__global__ __launch_bounds__(256) void gemm_kernel(
    const u16* __restrict__ A,    // [2048, 4096] bf16 row-major
    const u16* __restrict__ Bt,   // [4096, 4096] bf16, N-major (row n = output col)
    float*     __restrict__ C,    // [2048, 4096] fp32
    u16*       __restrict__ An)   // [2048, 4096] bf16, or nullptr
{
    __shared__ u16 lsA[128 * 32];
    __shared__ u16 lsB[128 * 32];

    const int tid = threadIdx.x;
    const int l   = tid & 63;
    const int w   = tid >> 6;
    const int wr  = w >> 1;   // wave row 0..1 (64 rows each)
    const int wc  = w & 1;    // wave col 0..1 (64 cols each)
    const int row0 = blockIdx.y << 7;   // 0..1920
    const int col0 = blockIdx.x << 7;   // 0..3968

    const u16* Ab = A  + ((size_t)row0 << 12);
    const u16* Bb = Bt + ((size_t)col0 << 12);

    // staging: 512 chunks of 16B per tile; thread handles chunks tid, tid+256
    const int c0 = tid, c1 = tid + 256;
    const size_t ga0 = ((size_t)(c0 >> 2) << 12) + ((c0 & 3) << 3);
    const size_t ga1 = ((size_t)(c1 >> 2) << 12) + ((c1 & 3) << 3);

    f32x4 acc[4][4];
    #pragma unroll
    for (int i = 0; i < 4; ++i)
        #pragma unroll
        for (int j = 0; j < 4; ++j)
            acc[i][j] = f32x4{0.f, 0.f, 0.f, 0.f};

    const int fr = l & 15;        // frag row/col within 16
    const int fq = l >> 4;        // k-group 0..3
    const int aoff = ((wr << 6) + fr) * 32 + (fq << 3);
    const int boff = ((wc << 6) + fr) * 32 + (fq << 3);

    for (int kt = 0; kt < 4096; kt += 32) {
        gld_lds16(Ab + ga0 + kt, &lsA[c0 << 3]);
        gld_lds16(Ab + ga1 + kt, &lsA[c1 << 3]);
        gld_lds16(Bb + ga0 + kt, &lsB[c0 << 3]);
        gld_lds16(Bb + ga1 + kt, &lsB[c1 << 3]);
        __syncthreads();   // compiler drains vmcnt before barrier

        bf16x8 af[4], bfv[4];
        #pragma unroll
        for (int i = 0; i < 4; ++i)
            af[i] = *reinterpret_cast<const bf16x8*>(&lsA[aoff + i * (16 * 32)]);
        #pragma unroll
        for (int j = 0; j < 4; ++j)
            bfv[j] = *reinterpret_cast<const bf16x8*>(&lsB[boff + j * (16 * 32)]);

        #pragma unroll
        for (int i = 0; i < 4; ++i)
            #pragma unroll
            for (int j = 0; j < 4; ++j)
                acc[i][j] = __builtin_amdgcn_mfma_f32_16x16x32_bf16(
                    af[i], bfv[j], acc[i][j], 0, 0, 0);
        __syncthreads();   // protect LDS before next stage
    }

    // epilogue: C/D layout (m89/m91): col = l&15, row = (l>>4)*4 + v
    #pragma unroll
    for (int i = 0; i < 4; ++i) {
        #pragma unroll
        for (int v = 0; v < 4; ++v) {
            const int r = row0 + (wr << 6) + (i << 4) + (fq << 2) + v;
            const size_t base = ((size_t)r << 12) + col0 + (wc << 6) + fr;
            #pragma unroll
            for (int j = 0; j < 4; ++j)
                C[base + (j << 4)] = acc[i][j][v];
            if (An != nullptr) {
                #pragma unroll
                for (int j = 0; j < 4; ++j)
                    An[base + (j << 4)] = f32_to_bf16(acc[i][j][v]);
            }
        }
    }
}

// ---------------- launcher ----------------
// inputs: x [2048,512,8] f32; w1,w2,w3 [512,512,8] f32
// output: [4, 2048, 512, 8] f32 = [x, a1, a2, a3]
// ws layout: A0 (16.78MB bf16) | A1 (16.78MB bf16) | Wmat (33.55MB bf16) = 67.1MB
extern "C" void kernel_launch(void* const* d_in, const int* in_sizes, int n_in,
                              void* d_out, int out_size, void* d_ws, size_t ws_size,
                              hipStream_t stream) {
    const float* x = (const float*)d_in[0];
    const float* wts[3] = {(const float*)d_in[1], (const float*)d_in[2],
                           (const float*)d_in[3]};
    float* out = (float*)d_out;

    constexpr size_t LAYER = (size_t)2048 * 4096;  // elems per activation

    u16* A0 = (u16*)d_ws;
    u16* A1 = A0 + LAYER;
    u16* Wm = A1 + LAYER;  // 4096*4096 bf16

    prep_kernel<<<dim3(8192), dim3(256), 0, stream>>>(x, out, A0);

    u16* Ac = A0;
    u16* Anx = A1;
    for (int L = 0; L < 3; ++L) {
        expand_kernel<<<dim3(8192), dim3(256), 0, stream>>>(wts[L], Wm);
        gemm_kernel<<<dim3(32, 16), dim3(256), 0, stream>>>(
            Ac, Wm, out + (size_t)(L + 1) * LAYER, (L == 2) ? nullptr : Anx);
        u16* t = Ac; Ac = Anx; Anx = t;
    }
}

// Round 2
// 394.338 us; speedup vs baseline: 1.2711x; 1.2711x over previous
//
#include <hip/hip_runtime.h>

// ---------------- types ----------------
using u16    = unsigned short;
using u32    = unsigned int;
using bf16x8 = __attribute__((ext_vector_type(8))) __bf16;
using f32x4  = __attribute__((ext_vector_type(4))) float;
using u16x4  = __attribute__((ext_vector_type(4))) u16;
using u16x8  = __attribute__((ext_vector_type(8))) u16;

__device__ __forceinline__ u16 f32_to_bf16(float f) {
    u32 u = __float_as_uint(f);
    u32 r = (u + 0x7FFFu + ((u >> 16) & 1u)) >> 16;  // RNE
    return (u16)r;
}

// async global->LDS, 16B per lane (literal size required)
__device__ __forceinline__ void gld_lds16(const void* g, void* l) {
    __builtin_amdgcn_global_load_lds(
        (const __attribute__((address_space(1))) u32*)g,
        (__attribute__((address_space(3))) u32*)l,
        16, 0, 0);
}

// Cl(3,0) reorder sign for e_a * e_b (metric all +1)
__device__ __forceinline__ float cl3_sign(int a, int b) {
    int swaps = __popc((a >> 1) & b) + __popc((a >> 2) & b);
    return (swaps & 1) ? -1.0f : 1.0f;
}

// ---------------- prep: out[0] = x (fp32 copy), A0 = bf16(x) ----------------
__global__ __launch_bounds__(256) void prep_kernel(
    const float* __restrict__ x, float* __restrict__ out0, u16* __restrict__ A0)
{
    const int t = blockIdx.x * 256 + threadIdx.x;
    const float4 v = reinterpret_cast<const float4*>(x)[t];
    reinterpret_cast<float4*>(out0)[t] = v;
    u16x4 b;
    b.x = f32_to_bf16(v.x);
    b.y = f32_to_bf16(v.y);
    b.z = f32_to_bf16(v.z);
    b.w = f32_to_bf16(v.w);
    reinterpret_cast<u16x4*>(A0)[t] = b;
}

// ---------------- expand: read w[o][i][*] ONCE, write all 8 blade-rows ----------------
// Wmat[(o*8+k)*4096 + i*8 + p] = sign(p,p^k) * w[o][i][p^k]
__global__ __launch_bounds__(256) void expand_kernel(
    const float* __restrict__ w, u16* __restrict__ Wm)
{
    const int t = blockIdx.x * 256 + threadIdx.x;  // 0..262143 = o*512+i
    const int o = t >> 9;
    const int i = t & 511;
    const float* src = w + ((size_t)t << 3);
    const float4 w0 = reinterpret_cast<const float4*>(src)[0];
    const float4 w1 = reinterpret_cast<const float4*>(src)[1];
    const float wv[8] = {w0.x, w0.y, w0.z, w0.w, w1.x, w1.y, w1.z, w1.w};
    #pragma unroll
    for (int kb = 0; kb < 8; ++kb) {
        u16x8 ov;
        #pragma unroll
        for (int p = 0; p < 8; ++p) {
            const int q = p ^ kb;
            ov[p] = f32_to_bf16(cl3_sign(p, q) * wv[q]);
        }
        reinterpret_cast<u16x8*>(Wm)[((size_t)(o * 8 + kb) << 9) + i] = ov;
    }
}

// ---------------- GEMM: 8-phase counted-vmcnt, 128x256 tile, BK=64 ----------------
// C[2048,4096] = A[2048,4096] x Bt[4096,4096]^T; grid 16x16 = 256 blocks (1/CU).
// 8 waves (2M x 4N), 64x64 per wave, 16x16x32 bf16 MFMA (4x4 frags x 2 k-slices).
// Tri-buffered LDS (3 x 48KB = 144KB), prefetch depth 2 K-tiles, vmcnt(6) steady.
// T2 swizzle: LDS[r][chunk] holds global chunk (chunk ^ (r&7)); gld_lds stays
// linear, the inverse permutation is applied to the per-lane GLOBAL address.
constexpr int BM = 128, BN = 256, BK = 64, KDIM = 4096, NKT = KDIM / BK;
constexpr int ASZ = BM * BK;        // 8192 u16
constexpr int BSZ = BN * BK;        // 16384 u16
constexpr int BUF = ASZ + BSZ;      // 24576 u16 = 48KB

__global__ __launch_bounds__(512, 2) void gemm8_kernel(
    const u16* __restrict__ A,   // [2048,4096] bf16 row-major
    const u16* __restrict__ Bt,  // [4096,4096] bf16, row n = output col
    float*     __restrict__ C,   // [2048,4096] fp32
    u16*       __restrict__ An)  // [2048,4096] bf16 or nullptr
{
    __shared__ __attribute__((aligned(16))) u16 lds[3 * BUF];  // 144KB

    const int tid = threadIdx.x;
    const int l   = tid & 63;
    const int w   = tid >> 6;        // wave 0..7
    const int wr  = w >> 2;          // 0..1
    const int wc  = w & 3;           // 0..3
    const int l8  = l >> 3, l7 = l & 7;
    const int fr  = l & 15, fq = l >> 4;
    const int row0 = blockIdx.y * BM;
    const int col0 = blockIdx.x * BN;

    // ---- staging helpers (one gld_lds = this wave's 8-row group, 1KB) ----
    auto stageA = [&](int buf, int kt, int q) {   // q in {0,1}
        const int g = q * 8 + w;                  // group 0..15
        const int r = g * 8 + l8;                 // tile row 0..127  (r&7 == l8)
        const u16* src = A + (size_t)(row0 + r) * KDIM + kt + ((l7 ^ l8) << 3);
        gld_lds16(src, &lds[buf * BUF + r * BK + l7 * 8]);
    };
    auto stageB = [&](int buf, int kt, int q) {   // q in {0..3}
        const int g = q * 8 + w;                  // group 0..31
        const int r = g * 8 + l8;                 // tile col 0..255
        const u16* src = Bt + (size_t)(col0 + r) * KDIM + kt + ((l7 ^ l8) << 3);
        gld_lds16(src, &lds[buf * BUF + ASZ + r * BK + l7 * 8]);
    };
    // ---- swizzled fragment reads ----
    auto rdA = [&](int buf, int mi, int ks) -> bf16x8 {
        const int r = wr * 64 + mi * 16 + fr;
        const int c = (ks * 4 + fq) ^ (r & 7);
        return *reinterpret_cast<const bf16x8*>(&lds[buf * BUF + r * BK + c * 8]);
    };
    auto rdB = [&](int buf, int ni, int ks) -> bf16x8 {
        const int r = wc * 64 + ni * 16 + fr;
        const int c = (ks * 4 + fq) ^ (r & 7);
        return *reinterpret_cast<const bf16x8*>(&lds[buf * BUF + ASZ + r * BK + c * 8]);
    };

    f32x4 acc[4][4];
    #pragma unroll
    for (int i = 0; i < 4; ++i)
        #pragma unroll
        for (int j = 0; j < 4; ++j)
            acc[i][j] = f32x4{0.f, 0.f, 0.f, 0.f};

    // ---- prologue: stage tiles 0 and 1 ----
    stageA(0, 0, 0); stageA(0, 0, 1);
    stageB(0, 0, 0); stageB(0, 0, 1); stageB(0, 0, 2); stageB(0, 0, 3);
    stageA(1, BK, 0); stageA(1, BK, 1);
    stageB(1, BK, 0); stageB(1, BK, 1); stageB(1, BK, 2); stageB(1, BK, 3);
    asm volatile("s_waitcnt vmcnt(6)" ::: "memory");   // tile0 landed
    __builtin_amdgcn_s_barrier();

    bf16x8 a0[2][2], a1[2][2], b0[2][2], b1[2][2];

    int cb = 0, nb = 2;
    for (int t = 0; t < NKT; ++t) {
        const int kt2 = (t + 2) * BK;
        const bool pre = (t + 2 < NKT);

        // phase 0: quad (mi 0-1, ni 0-1); read A01+B01; stage A of t+2
        #pragma unroll
        for (int mi = 0; mi < 2; ++mi)
            #pragma unroll
            for (int ks = 0; ks < 2; ++ks) a0[mi][ks] = rdA(cb, mi, ks);
        #pragma unroll
        for (int ni = 0; ni < 2; ++ni)
            #pragma unroll
            for (int ks = 0; ks < 2; ++ks) b0[ni][ks] = rdB(cb, ni, ks);
        if (pre) { stageA(nb, kt2, 0); stageA(nb, kt2, 1); }
        __builtin_amdgcn_s_barrier();
        asm volatile("s_waitcnt lgkmcnt(0)" ::: "memory");
        __builtin_amdgcn_sched_barrier(0);
        __builtin_amdgcn_s_setprio(1);
        #pragma unroll
        for (int mi = 0; mi < 2; ++mi)
            #pragma unroll
            for (int ni = 0; ni < 2; ++ni)
                #pragma unroll
                for (int ks = 0; ks < 2; ++ks)
                    acc[mi][ni] = __builtin_amdgcn_mfma_f32_16x16x32_bf16(
                        a0[mi][ks], b0[ni][ks], acc[mi][ni], 0, 0, 0);
        __builtin_amdgcn_s_setprio(0);
        __builtin_amdgcn_s_barrier();

        // phase 1: quad (0-1, 2-3); read B23 (reuse A01); stage B half 1
        #pragma unroll
        for (int ni = 0; ni < 2; ++ni)
            #pragma unroll
            for (int ks = 0; ks < 2; ++ks) b1[ni][ks] = rdB(cb, ni + 2, ks);
        if (pre) { stageB(nb, kt2, 0); stageB(nb, kt2, 1); }
        __builtin_amdgcn_s_barrier();
        asm volatile("s_waitcnt lgkmcnt(0)" ::: "memory");
        __builtin_amdgcn_sched_barrier(0);
        __builtin_amdgcn_s_setprio(1);
        #pragma unroll
        for (int mi = 0; mi < 2; ++mi)
            #pragma unroll
            for (int ni = 0; ni < 2; ++ni)
                #pragma unroll
                for (int ks = 0; ks < 2; ++ks)
                    acc[mi][ni + 2] = __builtin_amdgcn_mfma_f32_16x16x32_bf16(
                        a0[mi][ks], b1[ni][ks], acc[mi][ni + 2], 0, 0, 0);
        __builtin_amdgcn_s_setprio(0);
        __builtin_amdgcn_s_barrier();

        // phase 2: quad (2-3, 2-3); read A23 (reuse B23); stage B half 2
        #pragma unroll
        for (int mi = 0; mi < 2; ++mi)
            #pragma unroll
            for (int ks = 0; ks < 2; ++ks) a1[mi][ks] = rdA(cb, mi + 2, ks);
        if (pre) { stageB(nb, kt2, 2); stageB(nb, kt2, 3); }
        __builtin_amdgcn_s_barrier();
        asm volatile("s_waitcnt lgkmcnt(0)" ::: "memory");
        __builtin_amdgcn_sched_barrier(0);
        __builtin_amdgcn_s_setprio(1);
        #pragma unroll
        for (int mi = 0; mi < 2; ++mi)
            #pragma unroll
            for (int ni = 0; ni < 2; ++ni)
                #pragma unroll
                for (int ks = 0; ks < 2; ++ks)
                    acc[mi + 2][ni + 2] = __builtin_amdgcn_mfma_f32_16x16x32_bf16(
                        a1[mi][ks], b1[ni][ks], acc[mi + 2][ni + 2], 0, 0, 0);
        __builtin_amdgcn_s_setprio(0);
        __builtin_amdgcn_s_barrier();

        // phase 3: quad (2-3, 0-1); re-read B01 (reuse A23); no stage
        #pragma unroll
        for (int ni = 0; ni < 2; ++ni)
            #pragma unroll
            for (int ks = 0; ks < 2; ++ks) b0[ni][ks] = rdB(cb, ni, ks);
        __builtin_amdgcn_s_barrier();
        asm volatile("s_waitcnt lgkmcnt(0)" ::: "memory");
        __builtin_amdgcn_sched_barrier(0);
        __builtin_amdgcn_s_setprio(1);
        #pragma unroll
        for (int mi = 0; mi < 2; ++mi)
            #pragma unroll
            for (int ni = 0; ni < 2; ++ni)
                #pragma unroll
                for (int ks = 0; ks < 2; ++ks)
                    acc[mi + 2][ni] = __builtin_amdgcn_mfma_f32_16x16x32_bf16(
                        a1[mi][ks], b0[ni][ks], acc[mi + 2][ni], 0, 0, 0);
        __builtin_amdgcn_s_setprio(0);
        // end of iter: drain tile t+1's loads (keep t+2's 6 in flight)
        if (t + 2 < NKT)      { asm volatile("s_waitcnt vmcnt(6)" ::: "memory"); }
        else if (t + 1 < NKT) { asm volatile("s_waitcnt vmcnt(0)" ::: "memory"); }
        __builtin_amdgcn_s_barrier();

        cb = (cb == 2) ? 0 : cb + 1;
        nb = (nb == 2) ? 0 : nb + 1;
    }

    // ---- epilogue: C/D layout col = l&15, row = (l>>4)*4 + v ----
    #pragma unroll
    for (int mi = 0; mi < 4; ++mi) {
        #pragma unroll
        for (int v = 0; v < 4; ++v) {
            const int r = row0 + wr * 64 + mi * 16 + fq * 4 + v;
            const size_t base = ((size_t)r << 12) + col0 + wc * 64 + fr;
            #pragma unroll
            for (int ni = 0; ni < 4; ++ni)
                C[base + ni * 16] = acc[mi][ni][v];
            if (An != nullptr) {
                #pragma unroll
                for (int ni = 0; ni < 4; ++ni)
                    An[base + ni * 16] = f32_to_bf16(acc[mi][ni][v]);
            }
        }
    }
}

// ---------------- launcher ----------------
// ws layout: A0 (16.78MB bf16) | A1 (16.78MB bf16) | Wmat (33.55MB bf16)
extern "C" void kernel_launch(void* const* d_in, const int* in_sizes, int n_in,
                              void* d_out, int out_size, void* d_ws, size_t ws_size,
                              hipStream_t stream) {
    const float* x = (const float*)d_in[0];
    const float* wts[3] = {(const float*)d_in[1], (const float*)d_in[2],
                           (const float*)d_in[3]};
    float* out = (float*)d_out;

    constexpr size_t LAYER = (size_t)2048 * 4096;

    u16* A0 = (u16*)d_ws;
    u16* A1 = A0 + LAYER;
    u16* Wm = A1 + LAYER;

    prep_kernel<<<dim3(8192), dim3(256), 0, stream>>>(x, out, A0);

    u16* Ac = A0;
    u16* Anx = A1;
    for (int L = 0; L < 3; ++L) {
        expand_kernel<<<dim3(1024), dim3(256), 0, stream>>>(wts[L], Wm);
        gemm8_kernel<<<dim3(16, 16), dim3(512), 0, stream>>>(
            Ac, Wm, out + (size_t)(L + 1) * LAYER, (L == 2) ? nullptr : Anx);
        u16* t = Ac; Ac = Anx; Anx = t;
    }
}